// Round 3
// baseline (145.630 us; speedup 1.0000x reference)
//
#include <hip/hip_runtime.h>
#include <hip/hip_bf16.h>

#define NN 100000
#define NE 1600000
#define NF 128
#define UU 64

typedef __attribute__((ext_vector_type(8))) short short8;
typedef __attribute__((ext_vector_type(4))) float f32x4;
typedef __attribute__((ext_vector_type(4))) unsigned u32x4;

// ---------------- workspace layout (bytes) ----------------
static const size_t OFF_FLAG = 0;                               // 256
static const size_t OFF_H2   = 256;                             // NN*64*2 (bf16)
static const size_t OFF_AD   = OFF_H2  + (size_t)NN * UU * 2;   // NN*4
static const size_t OFF_AS   = OFF_AD  + (size_t)NN * 4;        // NN*4
static const size_t OFF_ROW  = OFF_AS  + (size_t)NN * 4;        // (NN+1)*4
static const size_t OFF_WP   = OFF_ROW + (size_t)(NN + 1) * 4;  // 8192 bf16 (16KB)

__device__ __forceinline__ unsigned short bfr(float v) {
    unsigned u = __float_as_uint(v);
    return (unsigned short)((u + 0x7FFFu + ((u >> 16) & 1u)) >> 16);
}

// packed f32x2 -> bf16x2 (RNE, matches bfr) — single HW instruction on gfx950.
__device__ __forceinline__ unsigned cvtpk(float lo, float hi) {
    unsigned r;
    asm("v_cvt_pk_bf16_f32 %0, %1, %2" : "=v"(r) : "v"(lo), "v"(hi));
    return r;
}

// prep: edge-format flag + W packed into MFMA B-fragment-linear bf16 layout.
__global__ __launch_bounds__(256) void prep(const int* __restrict__ ew,
                                            const float* __restrict__ W,
                                            int* __restrict__ flag,
                                            unsigned short* __restrict__ Wp) {
    if (blockIdx.x == 0) {
        if (threadIdx.x == 0) {
            int a = ew[2 * 400000 + 1] | ew[2 * 800000 + 1] |
                    ew[2 * 1200000 + 1] | ew[2 * 1599999 + 1];
            *flag = (a == 0) ? 1 : 0;   // 1 => int64
        }
        return;
    }
    int i = (blockIdx.x - 1) * 256 + threadIdx.x;   // 32*256 = 8192
    int j   = i & 7;
    int l15 = (i >> 3) & 15;
    int quad = (i >> 7) & 3;
    int kb  = (i >> 9) & 3;
    int nt  = i >> 11;
    Wp[i] = bfr(W[(size_t)(kb * 32 + quad * 8 + j) * UU + nt * 16 + l15]);
}

#define GEMM_BLOCKS   1563  // ceil(NN/64)
#define ROWS_BLOCKS   391   // ceil((NN+1)/256)

__global__ __launch_bounds__(256) void mega(const float* __restrict__ X,
                                            const void* __restrict__ edges,
                                            const int* __restrict__ flag,
                                            const unsigned short* __restrict__ Wp,
                                            const float* __restrict__ ka,
                                            unsigned short* __restrict__ h2,
                                            float* __restrict__ a_dst,
                                            float* __restrict__ a_src,
                                            int* __restrict__ rows) {
    int bid = blockIdx.x;
    int tid = threadIdx.x;

    if (bid < GEMM_BLOCKS) {
        // ---- MFMA GEMM: h = X @ W. Block = 64 nodes (4 waves x 16). ----
        int wv = tid >> 6, lane = tid & 63;
        int quad = lane >> 4, l15 = lane & 15;
        int nb = bid * 64 + wv * 16;
        int row = nb + l15; if (row >= NN) row = NN - 1;   // clamped: stores guarded
        const float* xr = X + (size_t)row * NF + quad * 8;

        short8 afrag[4];
#pragma unroll
        for (int kb = 0; kb < 4; kb++) {
            float4 p0 = *(const float4*)(xr + kb * 32);
            float4 p1 = *(const float4*)(xr + kb * 32 + 4);
            u32x4 aw;
            aw[0] = cvtpk(p0.x, p0.y); aw[1] = cvtpk(p0.z, p0.w);
            aw[2] = cvtpk(p1.x, p1.y); aw[3] = cvtpk(p1.z, p1.w);
            afrag[kb] = __builtin_bit_cast(short8, aw);
        }

        f32x4 acc[4] = {f32x4{0,0,0,0}, f32x4{0,0,0,0}, f32x4{0,0,0,0}, f32x4{0,0,0,0}};
        const short8* wpf = (const short8*)Wp;
#pragma unroll
        for (int nt = 0; nt < 4; nt++) {
#pragma unroll
            for (int kb = 0; kb < 4; kb++) {
                short8 b = wpf[((nt * 4 + kb) * 4 + quad) * 16 + l15];
                acc[nt] = __builtin_amdgcn_mfma_f32_16x16x32_bf16(afrag[kb], b, acc[nt], 0, 0, 0);
            }
        }

        float kad[4], kas[4];
#pragma unroll
        for (int nt = 0; nt < 4; nt++) {
            kad[nt] = ka[nt * 16 + l15];
            kas[nt] = ka[64 + nt * 16 + l15];
        }
#pragma unroll
        for (int r = 0; r < 4; r++) {
            int m = nb + quad * 4 + r;
            if (m < NN) {
#pragma unroll
                for (int nt = 0; nt < 4; nt++) {
                    unsigned v = cvtpk(acc[nt][r], acc[nt][r]);
                    h2[(size_t)m * UU + nt * 16 + l15] = (unsigned short)v;
                }
            }
            float pd = acc[0][r] * kad[0] + acc[1][r] * kad[1] + acc[2][r] * kad[2] + acc[3][r] * kad[3];
            float ps = acc[0][r] * kas[0] + acc[1][r] * kas[1] + acc[2][r] * kas[2] + acc[3][r] * kas[3];
            pd += __shfl_xor(pd, 1); pd += __shfl_xor(pd, 2);
            pd += __shfl_xor(pd, 4); pd += __shfl_xor(pd, 8);
            ps += __shfl_xor(ps, 1); ps += __shfl_xor(ps, 2);
            ps += __shfl_xor(ps, 4); ps += __shfl_xor(ps, 8);
            if (l15 == 0 && m < NN) { a_dst[m] = pd; a_src[m] = ps; }
        }
        return;
    }
    bid -= GEMM_BLOCKS;

    // ---- CSR row offsets by binary search on ORIGINAL edges ----
    {
        int n = bid * 256 + tid;
        if (n > NN) return;
        if (n == NN) { rows[NN] = NE; return; }
        int fl = *flag;
        const int* ew = (const int*)edges;
        int lo = 0, hi = NE;
        while (lo < hi) {
            int mid = (lo + hi) >> 1;
            int d = fl ? ew[4 * (size_t)mid] : ew[2 * (size_t)mid];
            if (d < n) lo = mid + 1; else hi = mid;
        }
        rows[n] = lo;
    }
}

__device__ __forceinline__ float edge_score(float ad, float as) {
    float sc = ad + as;
    sc = sc > 0.f ? sc : 0.2f * sc;
    sc = fminf(fmaxf(sc, -2.f), 2.f);
    return __expf(sc);
}

// One 16-lane group per node (4 nodes/wave, 16 nodes/block).
// Restructured fast path: issue the first 16 h2 row-gathers (which depend only on
// src indices) BEFORE the a_src/exp weight chain, so HBM/L3 latency of the gather
// hides under the weight computation. Sum-reduce/inv deferred to the store.
__global__ __launch_bounds__(256) void aggregate(const void* __restrict__ edges,
                                                 const int* __restrict__ flag,
                                                 const int* __restrict__ rows,
                                                 const float* __restrict__ a_dst,
                                                 const float* __restrict__ a_src,
                                                 const unsigned short* __restrict__ h2,
                                                 float* __restrict__ out) {
    int tid = threadIdx.x;
    int lane = tid & 63;
    int g = lane >> 4, gl = lane & 15;
    int n = blockIdx.x * 16 + (tid >> 6) * 4 + g;
    if (n >= NN) return;
    int s = rows[n], e = rows[n + 1];
    int cnt = e - s;
    float ad = a_dst[n];
    int fl = *flag;
    const int* ew = (const int*)edges;
    // src word: int64 fmt -> word 4*i+2 == (ew+2)[4*i]; int32 fmt -> word 2*i+1 == (ew+1)[2*i]
    const int* sp = ew + (fl ? 2 : 1);
    int lsh = fl ? 2 : 1;
    const unsigned short* h2g = h2 + gl * 4;
    int gbase = g * 16;
    float4 acc = make_float4(0.f, 0.f, 0.f, 0.f);
    float inv;

#define BATCH(MS, MW, BOFF)                                                  \
    {                                                                        \
        uint2 rr[4]; float sw[4]; int sjv[4];                                \
        _Pragma("unroll")                                                    \
        for (int t = 0; t < 4; t++) {                                        \
            sjv[t] = __shfl(MS, gbase + (BOFF) + t);                         \
            sw[t]  = __shfl(MW, gbase + (BOFF) + t);                         \
        }                                                                    \
        _Pragma("unroll")                                                    \
        for (int t = 0; t < 4; t++)                                          \
            rr[t] = *(const uint2*)(h2g + (size_t)sjv[t] * UU);              \
        _Pragma("unroll")                                                    \
        for (int t = 0; t < 4; t++) {                                        \
            acc.x += sw[t] * __uint_as_float(rr[t].x << 16);                 \
            acc.y += sw[t] * __uint_as_float(rr[t].x & 0xFFFF0000u);         \
            acc.z += sw[t] * __uint_as_float(rr[t].y << 16);                 \
            acc.w += sw[t] * __uint_as_float(rr[t].y & 0xFFFF0000u);         \
        }                                                                    \
    }

    if (cnt <= 64) {
        // 1) per-lane src indices (independent loads)
        int msrc[4];
#pragma unroll
        for (int k = 0; k < 4; k++) {
            int c = k * 16 + gl;
            msrc[k] = (c < cnt) ? sp[(size_t)(s + c) << lsh] : 0;
        }
        // 2) row indices for first 4 batches (edges 0..15) — VALU-only
        int sjv0[4][4];
#pragma unroll
        for (int b = 0; b < 4; b++)
#pragma unroll
            for (int t = 0; t < 4; t++)
                sjv0[b][t] = __shfl(msrc[0], gbase + b * 4 + t);
        // 3) ISSUE first 16 h2 row gathers (in flight while weights compute)
        uint2 rr0[4][4];
#pragma unroll
        for (int b = 0; b < 4; b++) {
            if (b * 4 < cnt) {
#pragma unroll
                for (int t = 0; t < 4; t++)
                    rr0[b][t] = *(const uint2*)(h2g + (size_t)sjv0[b][t] * UU);
            }
        }
        // 4) weight chain (a_src gather + exp) overlaps the gathers above
        float mw[4];
#pragma unroll
        for (int k = 0; k < 4; k++) {
            int c = k * 16 + gl;
            mw[k] = (c < cnt) ? edge_score(ad, a_src[msrc[k]]) : 0.f;
        }
        // 5) FMA for first 4 batches
#pragma unroll
        for (int b = 0; b < 4; b++) {
            if (b * 4 < cnt) {
#pragma unroll
                for (int t = 0; t < 4; t++) {
                    float w = __shfl(mw[0], gbase + b * 4 + t);
                    acc.x += w * __uint_as_float(rr0[b][t].x << 16);
                    acc.y += w * __uint_as_float(rr0[b][t].x & 0xFFFF0000u);
                    acc.z += w * __uint_as_float(rr0[b][t].y << 16);
                    acc.w += w * __uint_as_float(rr0[b][t].y & 0xFFFF0000u);
                }
            }
        }
        // 6) remaining batches (edges 16..63)
#pragma unroll
        for (int k = 1; k < 4; k++) {
#pragma unroll
            for (int b = 0; b < 4; b++) {
                if (k * 16 + b * 4 < cnt) BATCH(msrc[k], mw[k], b * 4);
            }
        }
        // 7) deferred denominator
        float t0 = (mw[0] + mw[1]) + (mw[2] + mw[3]);
        t0 += __shfl_xor(t0, 1); t0 += __shfl_xor(t0, 2);
        t0 += __shfl_xor(t0, 4); t0 += __shfl_xor(t0, 8);
        inv = (cnt > 0) ? 1.f / t0 : 0.f;
    } else {
        // rare fallback (Poisson(16) degree): two streaming passes with recompute
        float t0 = 0.f;
        for (int c = gl; c < cnt; c += 16) {
            int sj = sp[(size_t)(s + c) << lsh];
            t0 += edge_score(ad, a_src[sj]);
        }
        t0 += __shfl_xor(t0, 1); t0 += __shfl_xor(t0, 2);
        t0 += __shfl_xor(t0, 4); t0 += __shfl_xor(t0, 8);
        inv = 1.f / t0;
        for (int c0 = 0; c0 < cnt; c0 += 16) {
            int c = c0 + gl;
            int sj = 0; float w = 0.f;
            if (c < cnt) {
                sj = sp[(size_t)(s + c) << lsh];
                w = edge_score(ad, a_src[sj]);
            }
#pragma unroll
            for (int b = 0; b < 4; b++) {
                if (c0 + b * 4 < cnt) BATCH(sj, w, b * 4);
            }
        }
    }
#undef BATCH

    float4 o;
    o.x = acc.x * inv; o.y = acc.y * inv;
    o.z = acc.z * inv; o.w = acc.w * inv;
    *(float4*)(out + (size_t)n * UU + gl * 4) = o;
}

extern "C" void kernel_launch(void* const* d_in, const int* in_sizes, int n_in,
                              void* d_out, int out_size, void* d_ws, size_t ws_size,
                              hipStream_t stream) {
    const float* X  = (const float*)d_in[0];
    const void*  Ed = d_in[1];
    const float* W  = (const float*)d_in[2];
    const float* KA = (const float*)d_in[3];
    float* out = (float*)d_out;

    char* ws = (char*)d_ws;
    int*            flag  = (int*)(ws + OFF_FLAG);
    unsigned short* h2    = (unsigned short*)(ws + OFF_H2);
    float*          a_dst = (float*)(ws + OFF_AD);
    float*          a_src = (float*)(ws + OFF_AS);
    int*            rows  = (int*)(ws + OFF_ROW);
    unsigned short* Wp    = (unsigned short*)(ws + OFF_WP);

    prep<<<33, 256, 0, stream>>>((const int*)Ed, W, flag, Wp);
    mega<<<GEMM_BLOCKS + ROWS_BLOCKS, 256, 0, stream>>>(
        X, Ed, flag, Wp, KA, h2, a_dst, a_src, rows);
    aggregate<<<NN / 16, 256, 0, stream>>>(Ed, flag, rows, a_dst, a_src, h2, out);
}

// Round 5
// 144.066 us; speedup vs baseline: 1.0109x; 1.0109x over previous
//
#include <hip/hip_runtime.h>
#include <hip/hip_bf16.h>

#define NN 100000
#define NE 1600000
#define NF 128
#define UU 64

typedef __attribute__((ext_vector_type(8))) short short8;
typedef __attribute__((ext_vector_type(4))) float f32x4;
typedef __attribute__((ext_vector_type(2))) float f32x2;
typedef __attribute__((ext_vector_type(4))) unsigned u32x4;

// ---------------- workspace layout (bytes) ----------------
static const size_t OFF_FLAG = 0;                               // 256
static const size_t OFF_H2   = 256;                             // NN*64*2 (bf16)
static const size_t OFF_AD   = OFF_H2  + (size_t)NN * UU * 2;   // NN*4
static const size_t OFF_AS   = OFF_AD  + (size_t)NN * 4;        // NN*4
static const size_t OFF_ROW  = OFF_AS  + (size_t)NN * 4;        // (NN+1)*4
static const size_t OFF_WP   = OFF_ROW + (size_t)(NN + 1) * 4;  // 8192 bf16 (16KB)

__device__ __forceinline__ unsigned short bfr(float v) {
    unsigned u = __float_as_uint(v);
    return (unsigned short)((u + 0x7FFFu + ((u >> 16) & 1u)) >> 16);
}

// packed f32x2 -> bf16x2 (RNE, matches bfr) — single HW instruction on gfx950.
__device__ __forceinline__ unsigned cvtpk(float lo, float hi) {
    unsigned r;
    asm("v_cvt_pk_bf16_f32 %0, %1, %2" : "=v"(r) : "v"(lo), "v"(hi));
    return r;
}

// acc += {bf16lo(w32), bf16hi(w32)} * {s,s} — vector-typed so the backend can
// select v_pk_fma_f32 (VOP3P needs pair operands; falls back to 2x v_fmac).
__device__ __forceinline__ void pkfma(f32x2& acc, unsigned w32, float s) {
    f32x2 p, s2;
    p.x = __uint_as_float(w32 << 16);
    p.y = __uint_as_float(w32 & 0xFFFF0000u);
    s2.x = s; s2.y = s;
    acc = __builtin_elementwise_fma(p, s2, acc);
}

// prep: edge-format flag + W packed into MFMA B-fragment-linear bf16 layout.
__global__ __launch_bounds__(256) void prep(const int* __restrict__ ew,
                                            const float* __restrict__ W,
                                            int* __restrict__ flag,
                                            unsigned short* __restrict__ Wp) {
    if (blockIdx.x == 0) {
        if (threadIdx.x == 0) {
            int a = ew[2 * 400000 + 1] | ew[2 * 800000 + 1] |
                    ew[2 * 1200000 + 1] | ew[2 * 1599999 + 1];
            *flag = (a == 0) ? 1 : 0;   // 1 => int64
        }
        return;
    }
    int i = (blockIdx.x - 1) * 256 + threadIdx.x;   // 32*256 = 8192
    int j   = i & 7;
    int l15 = (i >> 3) & 15;
    int quad = (i >> 7) & 3;
    int kb  = (i >> 9) & 3;
    int nt  = i >> 11;
    Wp[i] = bfr(W[(size_t)(kb * 32 + quad * 8 + j) * UU + nt * 16 + l15]);
}

#define GEMM_BLOCKS   1563  // ceil(NN/64)
#define ROWS_BLOCKS   391   // ceil((NN+1)/256)

__global__ __launch_bounds__(256) void mega(const float* __restrict__ X,
                                            const void* __restrict__ edges,
                                            const int* __restrict__ flag,
                                            const unsigned short* __restrict__ Wp,
                                            const float* __restrict__ ka,
                                            unsigned short* __restrict__ h2,
                                            float* __restrict__ a_dst,
                                            float* __restrict__ a_src,
                                            int* __restrict__ rows) {
    int bid = blockIdx.x;
    int tid = threadIdx.x;

    if (bid < GEMM_BLOCKS) {
        // ---- MFMA GEMM: h = X @ W. Block = 64 nodes (4 waves x 16). ----
        int wv = tid >> 6, lane = tid & 63;
        int quad = lane >> 4, l15 = lane & 15;
        int nb = bid * 64 + wv * 16;
        int row = nb + l15; if (row >= NN) row = NN - 1;   // clamped: stores guarded
        const float* xr = X + (size_t)row * NF + quad * 8;

        short8 afrag[4];
#pragma unroll
        for (int kb = 0; kb < 4; kb++) {
            float4 p0 = *(const float4*)(xr + kb * 32);
            float4 p1 = *(const float4*)(xr + kb * 32 + 4);
            u32x4 aw;
            aw[0] = cvtpk(p0.x, p0.y); aw[1] = cvtpk(p0.z, p0.w);
            aw[2] = cvtpk(p1.x, p1.y); aw[3] = cvtpk(p1.z, p1.w);
            afrag[kb] = __builtin_bit_cast(short8, aw);
        }

        f32x4 acc[4] = {f32x4{0,0,0,0}, f32x4{0,0,0,0}, f32x4{0,0,0,0}, f32x4{0,0,0,0}};
        const short8* wpf = (const short8*)Wp;
#pragma unroll
        for (int nt = 0; nt < 4; nt++) {
#pragma unroll
            for (int kb = 0; kb < 4; kb++) {
                short8 b = wpf[((nt * 4 + kb) * 4 + quad) * 16 + l15];
                acc[nt] = __builtin_amdgcn_mfma_f32_16x16x32_bf16(afrag[kb], b, acc[nt], 0, 0, 0);
            }
        }

        float kad[4], kas[4];
#pragma unroll
        for (int nt = 0; nt < 4; nt++) {
            kad[nt] = ka[nt * 16 + l15];
            kas[nt] = ka[64 + nt * 16 + l15];
        }
#pragma unroll
        for (int r = 0; r < 4; r++) {
            int m = nb + quad * 4 + r;
            if (m < NN) {
#pragma unroll
                for (int nt = 0; nt < 4; nt++) {
                    unsigned v = cvtpk(acc[nt][r], acc[nt][r]);
                    h2[(size_t)m * UU + nt * 16 + l15] = (unsigned short)v;
                }
            }
            float pd = acc[0][r] * kad[0] + acc[1][r] * kad[1] + acc[2][r] * kad[2] + acc[3][r] * kad[3];
            float ps = acc[0][r] * kas[0] + acc[1][r] * kas[1] + acc[2][r] * kas[2] + acc[3][r] * kas[3];
            pd += __shfl_xor(pd, 1); pd += __shfl_xor(pd, 2);
            pd += __shfl_xor(pd, 4); pd += __shfl_xor(pd, 8);
            ps += __shfl_xor(ps, 1); ps += __shfl_xor(ps, 2);
            ps += __shfl_xor(ps, 4); ps += __shfl_xor(ps, 8);
            if (l15 == 0 && m < NN) { a_dst[m] = pd; a_src[m] = ps; }
        }
        return;
    }
    bid -= GEMM_BLOCKS;

    // ---- CSR row offsets by binary search on ORIGINAL edges ----
    {
        int n = bid * 256 + tid;
        if (n > NN) return;
        if (n == NN) { rows[NN] = NE; return; }
        int fl = *flag;
        const int* ew = (const int*)edges;
        int lo = 0, hi = NE;
        while (lo < hi) {
            int mid = (lo + hi) >> 1;
            int d = fl ? ew[4 * (size_t)mid] : ew[2 * (size_t)mid];
            if (d < n) lo = mid + 1; else hi = mid;
        }
        rows[n] = lo;
    }
}

__device__ __forceinline__ float edge_score(float ad, float as) {
    float sc = ad + as;
    sc = sc > 0.f ? sc : 0.2f * sc;
    sc = fminf(fmaxf(sc, -2.f), 2.f);
    return __expf(sc);
}

// One 16-lane group per node (4 nodes/wave, 16 nodes/block).
// Fast path: prefetch only the FIRST 2 batches (8 edges, 16 VGPR) of h2 rows
// before the a_src/exp weight chain — hides gather latency under the weight
// compute WITHOUT crossing the 64-VGPR occupancy tier (round-3 lesson).
__global__ __launch_bounds__(256) void aggregate(const void* __restrict__ edges,
                                                 const int* __restrict__ flag,
                                                 const int* __restrict__ rows,
                                                 const float* __restrict__ a_dst,
                                                 const float* __restrict__ a_src,
                                                 const unsigned short* __restrict__ h2,
                                                 float* __restrict__ out) {
    int tid = threadIdx.x;
    int lane = tid & 63;
    int g = lane >> 4, gl = lane & 15;
    int n = blockIdx.x * 16 + (tid >> 6) * 4 + g;
    if (n >= NN) return;
    int s = rows[n], e = rows[n + 1];
    int cnt = e - s;
    float ad = a_dst[n];
    int fl = *flag;
    const int* ew = (const int*)edges;
    // src word: int64 fmt -> word 4*i+2 == (ew+2)[4*i]; int32 fmt -> word 2*i+1 == (ew+1)[2*i]
    const int* sp = ew + (fl ? 2 : 1);
    int lsh = fl ? 2 : 1;
    const unsigned short* h2g = h2 + gl * 4;
    int gbase = g * 16;
    f32x2 acc01 = f32x2{0.f, 0.f};
    f32x2 acc23 = f32x2{0.f, 0.f};
    float inv;

#define BATCH(MS, MW, BOFF)                                                  \
    {                                                                        \
        uint2 rr[4]; float sw[4]; int sjv[4];                                \
        _Pragma("unroll")                                                    \
        for (int t = 0; t < 4; t++) {                                        \
            sjv[t] = __shfl(MS, gbase + (BOFF) + t);                         \
            sw[t]  = __shfl(MW, gbase + (BOFF) + t);                         \
        }                                                                    \
        _Pragma("unroll")                                                    \
        for (int t = 0; t < 4; t++)                                          \
            rr[t] = *(const uint2*)(h2g + (size_t)sjv[t] * UU);              \
        _Pragma("unroll")                                                    \
        for (int t = 0; t < 4; t++) {                                        \
            pkfma(acc01, rr[t].x, sw[t]);                                    \
            pkfma(acc23, rr[t].y, sw[t]);                                    \
        }                                                                    \
    }

    if (cnt <= 64) {
        // 1) per-lane src indices
        int msrc[4];
#pragma unroll
        for (int k = 0; k < 4; k++) {
            int c = k * 16 + gl;
            msrc[k] = (c < cnt) ? sp[(size_t)(s + c) << lsh] : 0;
        }
        // 2) prefetch: row indices + gathers for first 2 batches (8 edges).
        //    Unconditional — invalid lanes point at row 0; their weight is 0.
        int sjv0[2][4];
#pragma unroll
        for (int b = 0; b < 2; b++)
#pragma unroll
            for (int t = 0; t < 4; t++)
                sjv0[b][t] = __shfl(msrc[0], gbase + b * 4 + t);
        uint2 rr0[2][4];
#pragma unroll
        for (int b = 0; b < 2; b++)
#pragma unroll
            for (int t = 0; t < 4; t++)
                rr0[b][t] = *(const uint2*)(h2g + (size_t)sjv0[b][t] * UU);
        // 3) weight chain (a_src gather + exp) overlaps the in-flight gathers
        float mw[4];
#pragma unroll
        for (int k = 0; k < 4; k++) {
            int c = k * 16 + gl;
            mw[k] = (c < cnt) ? edge_score(ad, a_src[msrc[k]]) : 0.f;
        }
        // 4) FMA the prefetched batches (zero-weight lanes add 0 — no guards)
#pragma unroll
        for (int b = 0; b < 2; b++) {
#pragma unroll
            for (int t = 0; t < 4; t++) {
                float w = __shfl(mw[0], gbase + b * 4 + t);
                pkfma(acc01, rr0[b][t].x, w);
                pkfma(acc23, rr0[b][t].y, w);
            }
        }
        // 5) remaining batches
#pragma unroll
        for (int b = 2; b < 4; b++) {
            if (b * 4 < cnt) BATCH(msrc[0], mw[0], b * 4);
        }
#pragma unroll
        for (int k = 1; k < 4; k++) {
#pragma unroll
            for (int b = 0; b < 4; b++) {
                if (k * 16 + b * 4 < cnt) BATCH(msrc[k], mw[k], b * 4);
            }
        }
        // 6) deferred denominator
        float t0 = (mw[0] + mw[1]) + (mw[2] + mw[3]);
        t0 += __shfl_xor(t0, 1); t0 += __shfl_xor(t0, 2);
        t0 += __shfl_xor(t0, 4); t0 += __shfl_xor(t0, 8);
        inv = (cnt > 0) ? 1.f / t0 : 0.f;
    } else {
        // rare fallback (Poisson(16) degree): two streaming passes with recompute
        float t0 = 0.f;
        for (int c = gl; c < cnt; c += 16) {
            int sj = sp[(size_t)(s + c) << lsh];
            t0 += edge_score(ad, a_src[sj]);
        }
        t0 += __shfl_xor(t0, 1); t0 += __shfl_xor(t0, 2);
        t0 += __shfl_xor(t0, 4); t0 += __shfl_xor(t0, 8);
        inv = 1.f / t0;
        for (int c0 = 0; c0 < cnt; c0 += 16) {
            int c = c0 + gl;
            int sj = 0; float w = 0.f;
            if (c < cnt) {
                sj = sp[(size_t)(s + c) << lsh];
                w = edge_score(ad, a_src[sj]);
            }
#pragma unroll
            for (int b = 0; b < 4; b++) {
                if (c0 + b * 4 < cnt) BATCH(sj, w, b * 4);
            }
        }
    }
#undef BATCH

    float4 o;
    o.x = acc01.x * inv; o.y = acc01.y * inv;
    o.z = acc23.x * inv; o.w = acc23.y * inv;
    *(float4*)(out + (size_t)n * UU + gl * 4) = o;
}

extern "C" void kernel_launch(void* const* d_in, const int* in_sizes, int n_in,
                              void* d_out, int out_size, void* d_ws, size_t ws_size,
                              hipStream_t stream) {
    const float* X  = (const float*)d_in[0];
    const void*  Ed = d_in[1];
    const float* W  = (const float*)d_in[2];
    const float* KA = (const float*)d_in[3];
    float* out = (float*)d_out;

    char* ws = (char*)d_ws;
    int*            flag  = (int*)(ws + OFF_FLAG);
    unsigned short* h2    = (unsigned short*)(ws + OFF_H2);
    float*          a_dst = (float*)(ws + OFF_AD);
    float*          a_src = (float*)(ws + OFF_AS);
    int*            rows  = (int*)(ws + OFF_ROW);
    unsigned short* Wp    = (unsigned short*)(ws + OFF_WP);

    prep<<<33, 256, 0, stream>>>((const int*)Ed, W, flag, Wp);
    mega<<<GEMM_BLOCKS + ROWS_BLOCKS, 256, 0, stream>>>(
        X, Ed, flag, Wp, KA, h2, a_dst, a_src, rows);
    aggregate<<<(NN + 15) / 16, 256, 0, stream>>>(Ed, flag, rows, a_dst, a_src, h2, out);
}

// Round 6
// 142.966 us; speedup vs baseline: 1.0186x; 1.0077x over previous
//
#include <hip/hip_runtime.h>
#include <hip/hip_bf16.h>

#define NN 100000
#define NE 1600000
#define NF 128
#define UU 64

typedef __attribute__((ext_vector_type(8))) short short8;
typedef __attribute__((ext_vector_type(4))) float f32x4;
typedef __attribute__((ext_vector_type(2))) float f32x2;
typedef __attribute__((ext_vector_type(4))) unsigned u32x4;

// ---------------- workspace layout (bytes) ----------------
static const size_t OFF_H2   = 0;                               // NN*64*2 (bf16)
static const size_t OFF_AD   = OFF_H2  + (size_t)NN * UU * 2;   // NN*4
static const size_t OFF_AS   = OFF_AD  + (size_t)NN * 4;        // NN*4
static const size_t OFF_ROW  = OFF_AS  + (size_t)NN * 4;        // (NN+1)*4

// packed f32x2 -> bf16x2 (RNE) — single HW instruction on gfx950.
__device__ __forceinline__ unsigned cvtpk(float lo, float hi) {
    unsigned r;
    asm("v_cvt_pk_bf16_f32 %0, %1, %2" : "=v"(r) : "v"(lo), "v"(hi));
    return r;
}

// acc += {bf16lo(w32), bf16hi(w32)} * {s,s} — vector-typed so the backend can
// select v_pk_fma_f32 (falls back to 2x v_fmac).
__device__ __forceinline__ void pkfma(f32x2& acc, unsigned w32, float s) {
    f32x2 p, s2;
    p.x = __uint_as_float(w32 << 16);
    p.y = __uint_as_float(w32 & 0xFFFF0000u);
    s2.x = s; s2.y = s;
    acc = __builtin_elementwise_fma(p, s2, acc);
}

// edge-format probe: src upper-half words of 4 sample int64 edges are all 0
// iff layout is int64 (reads are in-bounds under both layouts; L1-hot).
__device__ __forceinline__ int edge_flag(const int* ew) {
    int a = ew[2 * 400000 + 1] | ew[2 * 800000 + 1] |
            ew[2 * 1200000 + 1] | ew[2 * 1599999 + 1];
    return (a == 0) ? 1 : 0;   // 1 => int64
}

#define GEMM_BLOCKS   1563  // ceil(NN/64)
#define ROWS_BLOCKS   391   // ceil((NN+1)/256)

// mega: MFMA GEMM h = X @ W (with per-block LDS W-packing — prep kernel gone),
// attention partials, and CSR row offsets. h2 row layout: [m][l15*4 + nt]
// (within-row permutation; coalesced uint2 stores here, same-byte gathers in
// aggregate which compensates in its output mapping).
__global__ __launch_bounds__(256) void mega(const float* __restrict__ X,
                                            const void* __restrict__ edges,
                                            const float* __restrict__ W,
                                            const float* __restrict__ ka,
                                            unsigned short* __restrict__ h2,
                                            float* __restrict__ a_dst,
                                            float* __restrict__ a_src,
                                            int* __restrict__ rows) {
    __shared__ unsigned Wl[4096];   // 16KB: W in MFMA B-fragment-linear bf16
    int bid = blockIdx.x;
    int tid = threadIdx.x;

    if (bid < GEMM_BLOCKS) {
        // ---- Block = 64 nodes (4 waves x 16). ----
        int wv = tid >> 6, lane = tid & 63;
        int quad = lane >> 4, l15 = lane & 15;
        int nb = bid * 64 + wv * 16;
        int row = nb + l15; if (row >= NN) row = NN - 1;   // clamped: stores guarded
        const float* xr = X + (size_t)row * NF + quad * 8;

        // 1) issue X-tile loads (latency hidden under W staging below)
        float4 p0[4], p1[4];
#pragma unroll
        for (int kb = 0; kb < 4; kb++) {
            p0[kb] = *(const float4*)(xr + kb * 32);
            p1[kb] = *(const float4*)(xr + kb * 32 + 4);
        }

        // 2) stage W -> LDS in fragment-linear layout.
        //    dword d holds {bf16 W[r0][c], bf16 W[r0+1][c]} with
        //    i0=2d: j=i0&7, l=(i0>>3)&15, q=(i0>>7)&3, kb=(i0>>9)&3, nt=i0>>11;
        //    r0 = kb*32+q*8+j, c = nt*16+l.  (j even -> j,j+1 pair along rows)
#pragma unroll
        for (int it = 0; it < 16; it++) {
            int d = it * 256 + tid;
            int i0 = d * 2;
            int j  = i0 & 7;
            int l  = (i0 >> 3) & 15;
            int q  = (i0 >> 7) & 3;
            int kb = (i0 >> 9) & 3;
            int nt = i0 >> 11;
            int r0 = kb * 32 + q * 8 + j;
            int c  = nt * 16 + l;
            float w0 = W[(size_t)r0 * UU + c];
            float w1 = W[(size_t)(r0 + 1) * UU + c];
            Wl[d] = cvtpk(w0, w1);
        }

        // 3) convert A-fragments (waits on X loads)
        short8 afrag[4];
#pragma unroll
        for (int kb = 0; kb < 4; kb++) {
            u32x4 aw;
            aw[0] = cvtpk(p0[kb].x, p0[kb].y); aw[1] = cvtpk(p0[kb].z, p0[kb].w);
            aw[2] = cvtpk(p1[kb].x, p1[kb].y); aw[3] = cvtpk(p1[kb].z, p1[kb].w);
            afrag[kb] = __builtin_bit_cast(short8, aw);
        }
        __syncthreads();

        f32x4 acc[4] = {f32x4{0,0,0,0}, f32x4{0,0,0,0}, f32x4{0,0,0,0}, f32x4{0,0,0,0}};
        const short8* wl8 = (const short8*)Wl;
#pragma unroll
        for (int nt = 0; nt < 4; nt++) {
#pragma unroll
            for (int kb = 0; kb < 4; kb++) {
                short8 b = wl8[((nt * 4 + kb) * 4 + quad) * 16 + l15];
                acc[nt] = __builtin_amdgcn_mfma_f32_16x16x32_bf16(afrag[kb], b, acc[nt], 0, 0, 0);
            }
        }

        float kad[4], kas[4];
#pragma unroll
        for (int nt = 0; nt < 4; nt++) {
            kad[nt] = ka[nt * 16 + l15];
            kas[nt] = ka[64 + nt * 16 + l15];
        }
#pragma unroll
        for (int r = 0; r < 4; r++) {
            int m = nb + quad * 4 + r;
            if (m < NN) {
                uint2 v;
                v.x = cvtpk(acc[0][r], acc[1][r]);   // nt=0,1 at p=l15*4+{0,1}
                v.y = cvtpk(acc[2][r], acc[3][r]);   // nt=2,3
                *(uint2*)(h2 + (size_t)m * UU + l15 * 4) = v;
            }
            float pd = acc[0][r] * kad[0] + acc[1][r] * kad[1] + acc[2][r] * kad[2] + acc[3][r] * kad[3];
            float ps = acc[0][r] * kas[0] + acc[1][r] * kas[1] + acc[2][r] * kas[2] + acc[3][r] * kas[3];
            pd += __shfl_xor(pd, 1); pd += __shfl_xor(pd, 2);
            pd += __shfl_xor(pd, 4); pd += __shfl_xor(pd, 8);
            ps += __shfl_xor(ps, 1); ps += __shfl_xor(ps, 2);
            ps += __shfl_xor(ps, 4); ps += __shfl_xor(ps, 8);
            if (l15 == 0 && m < NN) { a_dst[m] = pd; a_src[m] = ps; }
        }
        return;
    }
    bid -= GEMM_BLOCKS;

    // ---- CSR row offsets by binary search on ORIGINAL edges ----
    {
        int n = bid * 256 + tid;
        if (n > NN) return;
        const int* ew = (const int*)edges;
        if (n == NN) { rows[NN] = NE; return; }
        int fl = edge_flag(ew);
        int lo = 0, hi = NE;
        while (lo < hi) {
            int mid = (lo + hi) >> 1;
            int d = fl ? ew[4 * (size_t)mid] : ew[2 * (size_t)mid];
            if (d < n) lo = mid + 1; else hi = mid;
        }
        rows[n] = lo;
    }
}

__device__ __forceinline__ float edge_score(float ad, float as) {
    float sc = ad + as;
    sc = sc > 0.f ? sc : 0.2f * sc;
    sc = fminf(fmaxf(sc, -2.f), 2.f);
    return __expf(sc);
}

// One 16-lane group per node (4 nodes/wave, 16 nodes/block).
// 2-batch gather prefetch ahead of the weight chain; <=64 VGPR.
// h2 rows are within-row permuted: lane gl's uint2 holds cols {gl,16+gl} and
// {32+gl,48+gl}; output store maps accordingly (4x 64B-coalesced stores).
__global__ __launch_bounds__(256) void aggregate(const void* __restrict__ edges,
                                                 const int* __restrict__ rows,
                                                 const float* __restrict__ a_dst,
                                                 const float* __restrict__ a_src,
                                                 const unsigned short* __restrict__ h2,
                                                 float* __restrict__ out) {
    int tid = threadIdx.x;
    int lane = tid & 63;
    int g = lane >> 4, gl = lane & 15;
    int n = blockIdx.x * 16 + (tid >> 6) * 4 + g;
    if (n >= NN) return;
    int s = rows[n], e = rows[n + 1];
    int cnt = e - s;
    float ad = a_dst[n];
    const int* ew = (const int*)edges;
    int fl = edge_flag(ew);
    // src word: int64 fmt -> word 4*i+2 == (ew+2)[4*i]; int32 fmt -> word 2*i+1 == (ew+1)[2*i]
    const int* sp = ew + (fl ? 2 : 1);
    int lsh = fl ? 2 : 1;
    const unsigned short* h2g = h2 + gl * 4;
    int gbase = g * 16;
    f32x2 acc01 = f32x2{0.f, 0.f};
    f32x2 acc23 = f32x2{0.f, 0.f};
    float inv;

#define BATCH(MS, MW, BOFF)                                                  \
    {                                                                        \
        uint2 rr[4]; float sw[4]; int sjv[4];                                \
        _Pragma("unroll")                                                    \
        for (int t = 0; t < 4; t++) {                                        \
            sjv[t] = __shfl(MS, gbase + (BOFF) + t);                         \
            sw[t]  = __shfl(MW, gbase + (BOFF) + t);                         \
        }                                                                    \
        _Pragma("unroll")                                                    \
        for (int t = 0; t < 4; t++)                                          \
            rr[t] = *(const uint2*)(h2g + (size_t)sjv[t] * UU);              \
        _Pragma("unroll")                                                    \
        for (int t = 0; t < 4; t++) {                                        \
            pkfma(acc01, rr[t].x, sw[t]);                                    \
            pkfma(acc23, rr[t].y, sw[t]);                                    \
        }                                                                    \
    }

    if (cnt <= 64) {
        // 1) per-lane src indices
        int msrc[4];
#pragma unroll
        for (int k = 0; k < 4; k++) {
            int c = k * 16 + gl;
            msrc[k] = (c < cnt) ? sp[(size_t)(s + c) << lsh] : 0;
        }
        // 2) prefetch: row indices + gathers for first 2 batches (8 edges).
        int sjv0[2][4];
#pragma unroll
        for (int b = 0; b < 2; b++)
#pragma unroll
            for (int t = 0; t < 4; t++)
                sjv0[b][t] = __shfl(msrc[0], gbase + b * 4 + t);
        uint2 rr0[2][4];
#pragma unroll
        for (int b = 0; b < 2; b++)
#pragma unroll
            for (int t = 0; t < 4; t++)
                rr0[b][t] = *(const uint2*)(h2g + (size_t)sjv0[b][t] * UU);
        // 3) weight chain overlaps the in-flight gathers
        float mw[4];
#pragma unroll
        for (int k = 0; k < 4; k++) {
            int c = k * 16 + gl;
            mw[k] = (c < cnt) ? edge_score(ad, a_src[msrc[k]]) : 0.f;
        }
        // 4) FMA the prefetched batches (zero-weight lanes add 0)
#pragma unroll
        for (int b = 0; b < 2; b++) {
#pragma unroll
            for (int t = 0; t < 4; t++) {
                float w = __shfl(mw[0], gbase + b * 4 + t);
                pkfma(acc01, rr0[b][t].x, w);
                pkfma(acc23, rr0[b][t].y, w);
            }
        }
        // 5) remaining batches
#pragma unroll
        for (int b = 2; b < 4; b++) {
            if (b * 4 < cnt) BATCH(msrc[0], mw[0], b * 4);
        }
#pragma unroll
        for (int k = 1; k < 4; k++) {
#pragma unroll
            for (int b = 0; b < 4; b++) {
                if (k * 16 + b * 4 < cnt) BATCH(msrc[k], mw[k], b * 4);
            }
        }
        // 6) deferred denominator
        float t0 = (mw[0] + mw[1]) + (mw[2] + mw[3]);
        t0 += __shfl_xor(t0, 1); t0 += __shfl_xor(t0, 2);
        t0 += __shfl_xor(t0, 4); t0 += __shfl_xor(t0, 8);
        inv = (cnt > 0) ? 1.f / t0 : 0.f;
    } else {
        // rare fallback: two streaming passes with recompute
        float t0 = 0.f;
        for (int c = gl; c < cnt; c += 16) {
            int sj = sp[(size_t)(s + c) << lsh];
            t0 += edge_score(ad, a_src[sj]);
        }
        t0 += __shfl_xor(t0, 1); t0 += __shfl_xor(t0, 2);
        t0 += __shfl_xor(t0, 4); t0 += __shfl_xor(t0, 8);
        inv = 1.f / t0;
        for (int c0 = 0; c0 < cnt; c0 += 16) {
            int c = c0 + gl;
            int sj = 0; float w = 0.f;
            if (c < cnt) {
                sj = sp[(size_t)(s + c) << lsh];
                w = edge_score(ad, a_src[sj]);
            }
#pragma unroll
            for (int b = 0; b < 4; b++) {
                if (c0 + b * 4 < cnt) BATCH(sj, w, b * 4);
            }
        }
    }
#undef BATCH

    // lane gl owns cols {gl, 16+gl, 32+gl, 48+gl}; 4x 64B-coalesced stores
    float* outr = out + (size_t)n * UU + gl;
    outr[0]  = acc01.x * inv;
    outr[16] = acc01.y * inv;
    outr[32] = acc23.x * inv;
    outr[48] = acc23.y * inv;
}

extern "C" void kernel_launch(void* const* d_in, const int* in_sizes, int n_in,
                              void* d_out, int out_size, void* d_ws, size_t ws_size,
                              hipStream_t stream) {
    const float* X  = (const float*)d_in[0];
    const void*  Ed = d_in[1];
    const float* W  = (const float*)d_in[2];
    const float* KA = (const float*)d_in[3];
    float* out = (float*)d_out;

    char* ws = (char*)d_ws;
    unsigned short* h2    = (unsigned short*)(ws + OFF_H2);
    float*          a_dst = (float*)(ws + OFF_AD);
    float*          a_src = (float*)(ws + OFF_AS);
    int*            rows  = (int*)(ws + OFF_ROW);

    mega<<<GEMM_BLOCKS + ROWS_BLOCKS, 256, 0, stream>>>(
        X, Ed, W, KA, h2, a_dst, a_src, rows);
    aggregate<<<(NN + 15) / 16, 256, 0, stream>>>(Ed, rows, a_dst, a_src, h2, out);
}